// Round 8
// baseline (5918.806 us; speedup 1.0000x reference)
//
#include <hip/hip_runtime.h>

typedef __bf16 bf16;
typedef __attribute__((ext_vector_type(8))) __bf16 bf16x8;
typedef __attribute__((ext_vector_type(4))) float f32x4;

#define GLOBAL_AS __attribute__((address_space(1)))
#define LDS_AS __attribute__((address_space(3)))

__device__ __forceinline__ void gload_lds16(const void* g, void* l) {
  __builtin_amdgcn_global_load_lds((const GLOBAL_AS void*)g, (LDS_AS void*)l, 16, 0, 0);
}
// cache-bypassing variant (sc0|sc1 = system scope): coherent-read-through
__device__ __forceinline__ void gload_lds16_cc(const void* g, void* l) {
  __builtin_amdgcn_global_load_lds((const GLOBAL_AS void*)g, (LDS_AS void*)l, 16, 0, 0x11);
}

__device__ __forceinline__ f32x4 mfma16(bf16x8 a, bf16x8 b, f32x4 c) {
  return __builtin_amdgcn_mfma_f32_16x16x32_bf16(a, b, c, 0, 0, 0);
}

// ---------------- constants ----------------
#define T_SEQ 300
#define NBATCH 32
#define DIN 320
#define NH 1024
#define NG 4096              // 4*NH
#define MROWS 9600           // T_SEQ*NBATCH
#define OUT_Y 19660800       // T*B*2H
#define HN_SZ 196608         // 6*32*1024

// ---------------- f32 -> bf16 convert ----------------
__global__ __launch_bounds__(256) void k_cvt(const float* __restrict__ src,
                                             bf16* __restrict__ dst, int n8) {
  int stride = gridDim.x * blockDim.x;
  for (int i = blockIdx.x * blockDim.x + threadIdx.x; i < n8; i += stride) {
    const float* s = src + (size_t)i * 8;
    f32x4 a = *(const f32x4*)s;
    f32x4 b = *(const f32x4*)(s + 4);
    bf16x8 o;
#pragma unroll
    for (int j = 0; j < 4; ++j) { o[j] = (bf16)a[j]; o[j + 4] = (bf16)b[j]; }
    *(bf16x8*)(dst + (size_t)i * 8) = o;
  }
}

// ---------------- bias sums: bsum[l][dir][4096] = b_ih + b_hh ----------------
__global__ __launch_bounds__(256) void k_bsum(const float* __restrict__ bih0,
                                              const float* __restrict__ bhh0,
                                              const float* __restrict__ bihL,
                                              const float* __restrict__ bhhL,
                                              float* __restrict__ bsum) {
  int i = blockIdx.x * 256 + threadIdx.x;  // n = 6*4096 = 24576
  if (i < 2 * NG) bsum[i] = bih0[i] + bhh0[i];
  else            bsum[i] = bihL[i - 2 * NG] + bhhL[i - 2 * NG];
}

// ---------------- GX GEMM: gxT[dir][t][blk64][g][b][u16] = A*W^T + bias ----------------
__global__ __launch_bounds__(256) void k_gemm_gx(const bf16* __restrict__ A,
                                                 const bf16* __restrict__ Bw,
                                                 const float* __restrict__ bias,
                                                 bf16* __restrict__ gxout, int K) {
  __shared__ bf16 As[128 * 32];
  __shared__ bf16 Bs[128 * 32];
  const int t = threadIdx.x;
  const int m0 = blockIdx.y * 128, n0 = blockIdx.x * 128;
  const int lane = t & 63, wid = t >> 6;
  const int wr = wid >> 1, wc = wid & 1;
  const int fr = lane & 15, fq = lane >> 4;
  f32x4 acc[4][4] = {};
  for (int k0 = 0; k0 < K; k0 += 32) {
#pragma unroll
    for (int r = 0; r < 2; ++r) {
      int idx = r * 256 + t;
      int row = idx >> 2, kk = (idx & 3) * 8;
      gload_lds16(A + (size_t)(m0 + row) * K + k0 + kk, As + (size_t)idx * 8);
      gload_lds16(Bw + (size_t)(n0 + row) * K + k0 + kk, Bs + (size_t)idx * 8);
    }
    asm volatile("s_waitcnt vmcnt(0)" ::: "memory");
    __syncthreads();
    bf16x8 af[4], bf_[4];
#pragma unroll
    for (int i2 = 0; i2 < 4; ++i2) {
      af[i2]  = *(const bf16x8*)(As + (wr * 64 + i2 * 16 + fr) * 32 + fq * 8);
      bf_[i2] = *(const bf16x8*)(Bs + (wc * 64 + i2 * 16 + fr) * 32 + fq * 8);
    }
#pragma unroll
    for (int mi = 0; mi < 4; ++mi)
#pragma unroll
      for (int ni = 0; ni < 4; ++ni)
        acc[mi][ni] = mfma16(af[mi], bf_[ni], acc[mi][ni]);
    __syncthreads();
  }
  // epilogue: add bias, scatter to gxT[dir][t][blk][g][b][ul]
#pragma unroll
  for (int ni = 0; ni < 4; ++ni) {
    int col = n0 + wc * 64 + ni * 16 + fr;
    float bv = bias[col];
    int dirv = col >> 12, grow = col & (NG - 1);
    int gg = grow >> 10, uu = grow & 1023;
    int bidu = uu >> 4, ulo = uu & 15;
    bf16* base = gxout + ((size_t)dirv * 300 * 64 + bidu) * 2048 + gg * 512 + ulo;
#pragma unroll
    for (int mi = 0; mi < 4; ++mi) {
#pragma unroll
      for (int j = 0; j < 4; ++j) {
        int row = m0 + wr * 64 + mi * 16 + fq * 4 + j;
        int tt = row >> 5, b = row & 31;
        base[(size_t)tt * 131072 + b * 16] = (bf16)(acc[mi][ni][j] + bv);
      }
    }
  }
}

// ---------------- per-layer init: h buffer (par 0) + padded flags ----------------
__global__ __launch_bounds__(256) void k_init(const float* __restrict__ h0,
                                              bf16* __restrict__ hbuf,
                                              int* __restrict__ flags, int layer) {
  int i = blockIdx.x * 256 + threadIdx.x;  // 65536 = [2 dir][32][1024]
  hbuf[i] = (bf16)h0[(size_t)layer * 65536 + i];
  if (blockIdx.x == 0) {
    for (int j = threadIdx.x; j < 64 * 32; j += 256) flags[j] = 0;
  }
}

// ---------------- persistent recurrence: one launch per layer ----------------
// grid = 64 blocks x 512 threads. dir = bid>>5; block owns 32 hidden units.
// Wave w: K-quarter kh=w>>1, row-half rh=w&1 -> 64 gate-rows x K=256, W in 128 regs.
__global__ __launch_bounds__(512, 1) void k_rec(
    const bf16* __restrict__ whh,   // [2][4096][1024] (this layer)
    const bf16* __restrict__ gxT,   // [2][300][64][4][32][16] bf16, biases folded
    const float* __restrict__ h0,   // [6][32][1024]
    bf16* __restrict__ hbuf,        // [2 par][2 dir][32][1024]
    int* __restrict__ flags,        // [64*32], one 128B line per block flag
    bf16* __restrict__ yout,        // [9600][2048] or null (layer 2)
    float* __restrict__ dout,
    int layer) {
  __shared__ char smem_[115712];
  // [0..65536)        h tile (XOR-swizzled rows)
  // [65536..99328)    EXB exchange bf16 [4 kh][128 row][33]
  // [99328..115712)   gxl double-buffer [2][8192] bf16 bytes
  bf16* EXB = (bf16*)(smem_ + 65536);
  char* GXL = smem_ + 99328;

  const int tid = threadIdx.x;
  const int bid = blockIdx.x;
  const int dir = bid >> 5;
  const int rank = bid & 31;
  const int u0 = rank << 5;
  const int w = tid >> 6, lane = tid & 63;
  const int fr = lane & 15, fq = lane >> 4;
  const int kh = w >> 1, rh = w & 1;

  // ---- weights -> registers (64 rows x K=256 per wave = 128 regs/lane), pinned ----
  f32x4 wf[32];
#pragma unroll
  for (int rg = 0; rg < 4; ++rg) {
    int rowb = rh * 64 + rg * 16 + fr;  // block gate-row 0..127 (= g*32 + u_local)
    const bf16* Wp = whh + ((size_t)dir * 4096 + (rowb >> 5) * 1024 + u0 + (rowb & 31)) * 1024
                     + kh * 256 + fq * 8;
#pragma unroll
    for (int it = 0; it < 8; ++it) wf[rg * 8 + it] = *(const f32x4*)(Wp + it * 32);
  }
#pragma unroll
  for (int i = 0; i < 32; ++i) asm volatile("" : "+v"(wf[i]));

  // ---- cell state in registers; c init = h0 (reference's cn=hn bug) ----
  const int b_pt = tid >> 4;           // batch 0..31
  const int ul_pt = (tid & 15) << 1;   // local unit 0,2,..,30
  const int ug_pt = u0 + ul_pt;
  const size_t soff = ((size_t)layer * 2 + dir) * 32768 + (size_t)b_pt * 1024 + ug_pt;
  float c0 = h0[soff], c1 = h0[soff + 1];
  float hl0 = 0.f, hl1 = 0.f;

  // gx block slice for step t: 8KB contiguous at ((dir*300+t)*64 + 2*rank)*2048 elems
  const char* gx_blk = (const char*)(gxT + ((size_t)dir * 300 * 64 + 2 * rank) * 2048);
  // per-thread gx LDS byte offset within a buffer (chunk, gate later; pair of bf16)
  const int gx_rd = ((ul_pt >> 4) * 2048 + b_pt * 16 + (ul_pt & 15)) * 2;

  // h-stage source offsets (t-invariant): linear LDS dest, inverse-swizzled source
  int srcoff[8];
#pragma unroll
  for (int r = 0; r < 8; ++r) {
    int d = r * 8192 + tid * 16;
    int row = d >> 11, colb = d & 2047;
    srcoff[r] = row * 2048 + (colb ^ ((row & 7) << 4));
  }
  const int swz = (fr & 7) << 4;

  // ---- prologue: gx(0) DMA into buffer 0 ----
  {
    const int ts0 = dir ? (T_SEQ - 1) : 0;
    gload_lds16(gx_blk + (size_t)ts0 * 262144 + tid * 16, GXL + tid * 16);
  }

#pragma unroll 1
  for (int t = 0; t < T_SEQ; ++t) {
    // ---- barrier: all same-dir blocks published h(t-1); padded flag lines ----
    if (tid < 32) {
      while (__hip_atomic_load(&flags[(dir * 32 + tid) * 32], __ATOMIC_RELAXED,
                               __HIP_MEMORY_SCOPE_AGENT) < t)
        __builtin_amdgcn_s_sleep(1);
    }
    __syncthreads();   // execution order: no thread reads h before poll passes

    // ---- stage h(dir) 64KB -> LDS via coherence-point bypass loads ----
    const char* hsrc = (const char*)hbuf + (((size_t)(t & 1) * 2 + dir) << 16);
#pragma unroll
    for (int r = 0; r < 8; ++r)
      gload_lds16_cc(hsrc + srcoff[r], smem_ + r * 8192 + tid * 16);
    asm volatile("s_waitcnt vmcnt(0)" ::: "memory");   // h tile + gx(t) landed
    __syncthreads();

    // ---- matvec: K-split-4, 64 MFMA from LDS(h) x reg(W); 16KB LDS read/wave ----
    f32x4 acc[4][2] = {};
    const char* hb0 = smem_ + fr * 2048;
#pragma unroll
    for (int it = 0; it < 8; ++it) {
      int col = kh * 512 + it * 64 + fq * 16;
      bf16x8 ha0 = *(const bf16x8*)(hb0 + (col ^ swz));
      bf16x8 ha1 = *(const bf16x8*)(hb0 + 32768 + (col ^ swz));
#pragma unroll
      for (int rg = 0; rg < 4; ++rg) {
        bf16x8 wv = __builtin_bit_cast(bf16x8, wf[rg * 8 + it]);
        acc[rg][0] = mfma16(ha0, wv, acc[rg][0]);
        acc[rg][1] = mfma16(ha1, wv, acc[rg][1]);
      }
    }

    // ---- exchange K-partials via LDS, bf16, separate region (no alias barrier) ----
#pragma unroll
    for (int rg = 0; rg < 4; ++rg) {
      int rowb = rh * 64 + rg * 16 + fr;
      bf16* exr = EXB + (size_t)(kh * 128 + rowb) * 33;
#pragma unroll
      for (int j = 0; j < 4; ++j) {
        exr[fq * 4 + j]      = (bf16)acc[rg][0][j];   // batch = fq*4+j
        exr[16 + fq * 4 + j] = (bf16)acc[rg][1][j];   // batch = 16+fq*4+j
      }
    }
    __syncthreads();

    // ---- pointwise: 2 (b,u) pairs/thread; sum 4 K-partials + gx(LDS); c in regs ----
    const char* gxb = GXL + (t & 1) * 8192 + gx_rd;
    float hv[2]; float cc[2] = {c0, c1};
    unsigned gxw[4];
#pragma unroll
    for (int g2 = 0; g2 < 4; ++g2) gxw[g2] = *(const unsigned*)(gxb + g2 * 1024);
#pragma unroll
    for (int q = 0; q < 2; ++q) {
      int ul = ul_pt + q;
      float gt[4];
#pragma unroll
      for (int g2 = 0; g2 < 4; ++g2) {
        int rowb = g2 * 32 + ul;
        float s = (float)EXB[(size_t)(0 * 128 + rowb) * 33 + b_pt]
                + (float)EXB[(size_t)(1 * 128 + rowb) * 33 + b_pt]
                + (float)EXB[(size_t)(2 * 128 + rowb) * 33 + b_pt]
                + (float)EXB[(size_t)(3 * 128 + rowb) * 33 + b_pt];
        unsigned gb = (q == 0) ? ((gxw[g2] & 0xffffu) << 16) : (gxw[g2] & 0xffff0000u);
        gt[g2] = s + __builtin_bit_cast(float, gb);
      }
      float iv = fminf(fmaxf(__builtin_fmaf(0.2f, gt[0], 0.5f), 0.f), 1.f);
      float fv = fminf(fmaxf(__builtin_fmaf(0.2f, gt[1], 0.5f), 0.f), 1.f);
      float gv = fminf(fmaxf(gt[2], -1.f), 1.f);
      float ov = fminf(fmaxf(__builtin_fmaf(0.2f, gt[3], 0.5f), 0.f), 1.f);
      float c = fv * cc[q] + iv * gv;
      cc[q] = c;
      hv[q] = ov * fminf(fmaxf(c, -1.f), 1.f);
    }
    c0 = cc[0]; c1 = cc[1]; hl0 = hv[0]; hl1 = hv[1];

    // ---- issue gx(t+1) DMA (other buffer; drains with the publish ack) ----
    if (t + 1 < T_SEQ) {
      const int tn = dir ? (T_SEQ - 2 - t) : (t + 1);
      gload_lds16(gx_blk + (size_t)tn * 262144 + tid * 16,
                  GXL + ((t + 1) & 1) * 8192 + tid * 16);
    }

    // ---- publish h (write-through), drain, flag, then y stores ----
    unsigned hp;
    { union { bf16 h[2]; unsigned u; } pk; pk.h[0] = (bf16)hv[0]; pk.h[1] = (bf16)hv[1]; hp = pk.u; }
    volatile unsigned* hdst =
        (volatile unsigned*)((char*)hbuf + (((size_t)((t + 1) & 1) * 2 + dir) << 16))
        + (((size_t)b_pt * 1024 + ug_pt) >> 1);
    *hdst = hp;
    asm volatile("s_waitcnt vmcnt(0)" ::: "memory");
    __syncthreads();   // all h stores at coherence point before flag release
    if (tid == 0)
      __hip_atomic_store(&flags[bid * 32], t + 1, __ATOMIC_RELAXED, __HIP_MEMORY_SCOPE_AGENT);
    const int tseq = dir ? (T_SEQ - 1 - t) : t;
    if (yout) {
      *(unsigned*)((char*)yout + (((size_t)tseq * 32 + b_pt) * 2048 + dir * 1024 + ug_pt) * 2) = hp;
    } else {
      float* yd = dout + ((size_t)tseq * 32 + b_pt) * 2048 + dir * 1024 + ug_pt;
      yd[0] = hv[0]; yd[1] = hv[1];
    }
  }

  // ---- final (h,c) states from registers ----
  dout[OUT_Y + soff] = hl0;
  dout[OUT_Y + soff + 1] = hl1;
  dout[OUT_Y + HN_SZ + soff] = c0;
  dout[OUT_Y + HN_SZ + soff + 1] = c1;
}

// ---------------- host launcher ----------------
extern "C" void kernel_launch(void* const* d_in, const int* in_sizes, int n_in,
                              void* d_out, int out_size, void* d_ws, size_t ws_size,
                              hipStream_t stream) {
  const float* x     = (const float*)d_in[0];
  const float* h0    = (const float*)d_in[1];
  // d_in[2] = c0: unused (reference init bug: cn = hn = h0)
  const float* w_ih0 = (const float*)d_in[3];
  const float* w_hh0 = (const float*)d_in[4];
  const float* b_ih0 = (const float*)d_in[5];
  const float* b_hh0 = (const float*)d_in[6];
  const float* w_ihL = (const float*)d_in[7];
  const float* w_hhL = (const float*)d_in[8];
  const float* b_ihL = (const float*)d_in[9];
  const float* b_hhL = (const float*)d_in[10];
  float* dout = (float*)d_out;
  char* ws = (char*)d_ws;

  // ---- workspace carve (bytes) ----
  const size_t OFF_XB   = 0;                         // bf16 [9600][320]
  const size_t OFF_WIH0 = 6144000;                   // bf16 [8192][320]
  const size_t OFF_WIHL = 11386880;                  // bf16 [2][8192][2048]
  const size_t OFF_WHH  = 78495744;                  // bf16 [6][4096][1024]
  const size_t OFF_BSUM = 128827392;                 // f32  [6][4096]
  const size_t OFF_GX   = 128925696;                 // bf16 [2][300][64][4][32][16]
  const size_t OFF_Y0   = 286212096;                 // bf16 [9600][2048]
  const size_t OFF_Y1   = 325533696;                 // bf16 [9600][2048]
  const size_t OFF_HBF  = 364855296;                 // bf16 [2 par][2 dir][32][1024]
  const size_t OFF_FLG  = 365117440;                 // int  [64*32] (128B-padded flags)

  bf16*  xb    = (bf16*)(ws + OFF_XB);
  bf16*  wih0b = (bf16*)(ws + OFF_WIH0);
  bf16*  wihLb = (bf16*)(ws + OFF_WIHL);
  bf16*  whhb  = (bf16*)(ws + OFF_WHH);
  float* bsum  = (float*)(ws + OFF_BSUM);
  bf16*  gx    = (bf16*)(ws + OFF_GX);
  bf16*  y0    = (bf16*)(ws + OFF_Y0);
  bf16*  y1    = (bf16*)(ws + OFF_Y1);
  bf16*  hbuf  = (bf16*)(ws + OFF_HBF);
  int*   flags = (int*)(ws + OFF_FLG);

  auto cvt = [&](const float* s, bf16* d, size_t n) {
    int n8 = (int)(n / 8);
    int grid = (n8 + 255) / 256; if (grid > 2048) grid = 2048;
    k_cvt<<<grid, 256, 0, stream>>>(s, d, n8);
  };

  cvt(x,     xb,    (size_t)MROWS * DIN);
  cvt(w_ih0, wih0b, (size_t)2 * NG * DIN);
  cvt(w_ihL, wihLb, (size_t)2 * 2 * NG * 2048);
  cvt(w_hh0, whhb,  (size_t)2 * NG * NH);
  cvt(w_hhL, whhb + (size_t)2 * NG * NH, (size_t)4 * NG * NH);
  k_bsum<<<96, 256, 0, stream>>>(b_ih0, b_hh0, b_ihL, b_hhL, bsum);

  for (int l = 0; l < 3; ++l) {
    const bf16* A = (l == 0) ? xb : (l == 1 ? y0 : y1);
    int K = (l == 0) ? DIN : 2048;
    const bf16* Bw = (l == 0) ? wih0b : (wihLb + (size_t)(l - 1) * 2 * NG * 2048);
    k_gemm_gx<<<dim3(64, 75), 256, 0, stream>>>(A, Bw, bsum + (size_t)l * 2 * NG, gx, K);

    k_init<<<256, 256, 0, stream>>>(h0, hbuf, flags, l);

    const bf16* whh_l = whhb + (size_t)l * 2 * NG * NH;
    bf16* yout = (l == 0) ? y0 : (l == 1 ? y1 : nullptr);
    k_rec<<<64, 512, 0, stream>>>(whh_l, gx, h0, hbuf, flags, yout, dout, l);
  }
  (void)in_sizes; (void)n_in; (void)out_size; (void)ws_size;
}

// Round 9
// 5866.273 us; speedup vs baseline: 1.0090x; 1.0090x over previous
//
#include <hip/hip_runtime.h>

typedef __bf16 bf16;
typedef __attribute__((ext_vector_type(8))) __bf16 bf16x8;
typedef __attribute__((ext_vector_type(4))) float f32x4;

#define GLOBAL_AS __attribute__((address_space(1)))
#define LDS_AS __attribute__((address_space(3)))

__device__ __forceinline__ void gload_lds16(const void* g, void* l) {
  __builtin_amdgcn_global_load_lds((const GLOBAL_AS void*)g, (LDS_AS void*)l, 16, 0, 0);
}
// cache-bypassing variant (sc0|sc1 = system scope): coherent-read-through
__device__ __forceinline__ void gload_lds16_cc(const void* g, void* l) {
  __builtin_amdgcn_global_load_lds((const GLOBAL_AS void*)g, (LDS_AS void*)l, 16, 0, 0x11);
}

__device__ __forceinline__ f32x4 mfma16(bf16x8 a, bf16x8 b, f32x4 c) {
  return __builtin_amdgcn_mfma_f32_16x16x32_bf16(a, b, c, 0, 0, 0);
}

// ---------------- constants ----------------
#define T_SEQ 300
#define NBATCH 32
#define DIN 320
#define NH 1024
#define NG 4096              // 4*NH
#define MROWS 9600           // T_SEQ*NBATCH
#define OUT_Y 19660800       // T*B*2H
#define HN_SZ 196608         // 6*32*1024

// ---------------- f32 -> bf16 convert ----------------
__global__ __launch_bounds__(256) void k_cvt(const float* __restrict__ src,
                                             bf16* __restrict__ dst, int n8) {
  int stride = gridDim.x * blockDim.x;
  for (int i = blockIdx.x * blockDim.x + threadIdx.x; i < n8; i += stride) {
    const float* s = src + (size_t)i * 8;
    f32x4 a = *(const f32x4*)s;
    f32x4 b = *(const f32x4*)(s + 4);
    bf16x8 o;
#pragma unroll
    for (int j = 0; j < 4; ++j) { o[j] = (bf16)a[j]; o[j + 4] = (bf16)b[j]; }
    *(bf16x8*)(dst + (size_t)i * 8) = o;
  }
}

// ---------------- bias sums: bsum[l][dir][4096] = b_ih + b_hh ----------------
__global__ __launch_bounds__(256) void k_bsum(const float* __restrict__ bih0,
                                              const float* __restrict__ bhh0,
                                              const float* __restrict__ bihL,
                                              const float* __restrict__ bhhL,
                                              float* __restrict__ bsum) {
  int i = blockIdx.x * 256 + threadIdx.x;  // n = 6*4096 = 24576
  if (i < 2 * NG) bsum[i] = bih0[i] + bhh0[i];
  else            bsum[i] = bihL[i - 2 * NG] + bhhL[i - 2 * NG];
}

// ---------------- GX GEMM: gxT[dir][t][blk64][g][b][u16] = A*W^T + bias ----------------
__global__ __launch_bounds__(256) void k_gemm_gx(const bf16* __restrict__ A,
                                                 const bf16* __restrict__ Bw,
                                                 const float* __restrict__ bias,
                                                 bf16* __restrict__ gxout, int K) {
  __shared__ bf16 As[128 * 32];
  __shared__ bf16 Bs[128 * 32];
  const int t = threadIdx.x;
  const int m0 = blockIdx.y * 128, n0 = blockIdx.x * 128;
  const int lane = t & 63, wid = t >> 6;
  const int wr = wid >> 1, wc = wid & 1;
  const int fr = lane & 15, fq = lane >> 4;
  f32x4 acc[4][4] = {};
  for (int k0 = 0; k0 < K; k0 += 32) {
#pragma unroll
    for (int r = 0; r < 2; ++r) {
      int idx = r * 256 + t;
      int row = idx >> 2, kk = (idx & 3) * 8;
      gload_lds16(A + (size_t)(m0 + row) * K + k0 + kk, As + (size_t)idx * 8);
      gload_lds16(Bw + (size_t)(n0 + row) * K + k0 + kk, Bs + (size_t)idx * 8);
    }
    asm volatile("s_waitcnt vmcnt(0)" ::: "memory");
    __syncthreads();
    bf16x8 af[4], bf_[4];
#pragma unroll
    for (int i2 = 0; i2 < 4; ++i2) {
      af[i2]  = *(const bf16x8*)(As + (wr * 64 + i2 * 16 + fr) * 32 + fq * 8);
      bf_[i2] = *(const bf16x8*)(Bs + (wc * 64 + i2 * 16 + fr) * 32 + fq * 8);
    }
#pragma unroll
    for (int mi = 0; mi < 4; ++mi)
#pragma unroll
      for (int ni = 0; ni < 4; ++ni)
        acc[mi][ni] = mfma16(af[mi], bf_[ni], acc[mi][ni]);
    __syncthreads();
  }
  // epilogue: add bias, scatter to gxT[dir][t][blk][g][b][ul]
#pragma unroll
  for (int ni = 0; ni < 4; ++ni) {
    int col = n0 + wc * 64 + ni * 16 + fr;
    float bv = bias[col];
    int dirv = col >> 12, grow = col & (NG - 1);
    int gg = grow >> 10, uu = grow & 1023;
    int bidu = uu >> 4, ulo = uu & 15;
    bf16* base = gxout + ((size_t)dirv * 300 * 64 + bidu) * 2048 + gg * 512 + ulo;
#pragma unroll
    for (int mi = 0; mi < 4; ++mi) {
#pragma unroll
      for (int j = 0; j < 4; ++j) {
        int row = m0 + wr * 64 + mi * 16 + fq * 4 + j;
        int tt = row >> 5, b = row & 31;
        base[(size_t)tt * 131072 + b * 16] = (bf16)(acc[mi][ni][j] + bv);
      }
    }
  }
}

// ---------------- per-layer init: h buffer (par 0) + padded flags ----------------
__global__ __launch_bounds__(256) void k_init(const float* __restrict__ h0,
                                              bf16* __restrict__ hbuf,
                                              int* __restrict__ flags, int layer) {
  int i = blockIdx.x * 256 + threadIdx.x;  // 65536 = [2 dir][32][1024]
  hbuf[i] = (bf16)h0[(size_t)layer * 65536 + i];
  if (blockIdx.x == 0) {
    for (int j = threadIdx.x; j < 64 * 32; j += 256) flags[j] = 0;
  }
}

// ---------------- persistent recurrence: one launch per layer ----------------
// grid = 64 blocks x 512 threads. dir = bid>>5; block owns 32 hidden units.
// Wave w: K-quarter kh=w>>1, row-half rh=w&1 -> 64 gate-rows x K=256, W in 128 regs.
// Loop skeleton = round-5 (proven 1244 us/layer): gx DMA issued BEFORE the poll so
// its HBM latency drains under poll + h-stage; publish drain waits only on h stores.
__global__ __launch_bounds__(512, 1) void k_rec(
    const bf16* __restrict__ whh,   // [2][4096][1024] (this layer)
    const bf16* __restrict__ gxT,   // [2][300][64][4][32][16] bf16, biases folded
    const float* __restrict__ h0,   // [6][32][1024]
    bf16* __restrict__ hbuf,        // [2 par][2 dir][32][1024]
    int* __restrict__ flags,        // [64*32], one 128B line per block flag
    bf16* __restrict__ yout,        // [9600][2048] or null (layer 2)
    float* __restrict__ dout,
    int layer) {
  __shared__ char smem_[107520];
  // [0..65536)        h tile (XOR-swizzled rows)
  // [65536..99328)    EXB exchange bf16 [4 kh][128 row][33]
  // [99328..107520)   GXL gx tile [2 chunk][4 g][32 b][16 u] bf16 = 8 KB
  bf16* EXB = (bf16*)(smem_ + 65536);
  char* GXL = smem_ + 99328;

  const int tid = threadIdx.x;
  const int bid = blockIdx.x;
  const int dir = bid >> 5;
  const int rank = bid & 31;
  const int u0 = rank << 5;
  const int w = tid >> 6, lane = tid & 63;
  const int fr = lane & 15, fq = lane >> 4;
  const int kh = w >> 1, rh = w & 1;

  // ---- weights -> registers (64 rows x K=256 per wave = 128 regs/lane), pinned ----
  f32x4 wf[32];
#pragma unroll
  for (int rg = 0; rg < 4; ++rg) {
    int rowb = rh * 64 + rg * 16 + fr;  // block gate-row 0..127 (= g*32 + u_local)
    const bf16* Wp = whh + ((size_t)dir * 4096 + (rowb >> 5) * 1024 + u0 + (rowb & 31)) * 1024
                     + kh * 256 + fq * 8;
#pragma unroll
    for (int it = 0; it < 8; ++it) wf[rg * 8 + it] = *(const f32x4*)(Wp + it * 32);
  }
#pragma unroll
  for (int i = 0; i < 32; ++i) asm volatile("" : "+v"(wf[i]));

  // ---- cell state in registers; c init = h0 (reference's cn=hn bug) ----
  const int b_pt = tid >> 4;           // batch 0..31
  const int ul_pt = (tid & 15) << 1;   // local unit 0,2,..,30
  const int ug_pt = u0 + ul_pt;
  const size_t soff = ((size_t)layer * 2 + dir) * 32768 + (size_t)b_pt * 1024 + ug_pt;
  float c0 = h0[soff], c1 = h0[soff + 1];
  float hl0 = 0.f, hl1 = 0.f;

  // gx block slice: 8KB contiguous per (dir,t) at chunks [2*rank, 2*rank+2)
  const char* gx_blk = (const char*)(gxT + ((size_t)dir * 300 * 64 + 2 * rank) * 2048);
  // per-thread gx LDS byte offset (chunk-half, b, u-pair)
  const int gx_rd = ((ul_pt >> 4) * 2048 + b_pt * 16 + (ul_pt & 15)) * 2;

  // h-stage source offsets (t-invariant): linear LDS dest, inverse-swizzled source
  int srcoff[8];
#pragma unroll
  for (int r = 0; r < 8; ++r) {
    int d = r * 8192 + tid * 16;
    int row = d >> 11, colb = d & 2047;
    srcoff[r] = row * 2048 + (colb ^ ((row & 7) << 4));
  }
  const int swz = (fr & 7) << 4;

#pragma unroll 1
  for (int t = 0; t < T_SEQ; ++t) {
    const int tseq = dir ? (T_SEQ - 1 - t) : t;

    // ---- gx(t) DMA issue FIRST (latency hides under poll + h-stage) ----
    gload_lds16(gx_blk + (size_t)tseq * 262144 + tid * 16, GXL + tid * 16);

    // ---- barrier: all same-dir blocks published h(t-1); padded flag lines ----
    if (tid < 32) {
      while (__hip_atomic_load(&flags[(dir * 32 + tid) * 32], __ATOMIC_RELAXED,
                               __HIP_MEMORY_SCOPE_AGENT) < t)
        __builtin_amdgcn_s_sleep(1);
    }
    __syncthreads();   // execution order: no thread reads h before poll passes

    // ---- stage h(dir) 64KB -> LDS via coherence-point bypass loads ----
    const char* hsrc = (const char*)hbuf + (((size_t)(t & 1) * 2 + dir) << 16);
#pragma unroll
    for (int r = 0; r < 8; ++r)
      gload_lds16_cc(hsrc + srcoff[r], smem_ + r * 8192 + tid * 16);
    asm volatile("s_waitcnt vmcnt(0)" ::: "memory");   // h tile + gx(t) landed
    __syncthreads();

    // ---- matvec: K-split-4, 64 MFMA from LDS(h) x reg(W); 16KB LDS read/wave ----
    f32x4 acc[4][2] = {};
    const char* hb0 = smem_ + fr * 2048;
#pragma unroll
    for (int it = 0; it < 8; ++it) {
      int col = kh * 512 + it * 64 + fq * 16;
      bf16x8 ha0 = *(const bf16x8*)(hb0 + (col ^ swz));
      bf16x8 ha1 = *(const bf16x8*)(hb0 + 32768 + (col ^ swz));
#pragma unroll
      for (int rg = 0; rg < 4; ++rg) {
        bf16x8 wv = __builtin_bit_cast(bf16x8, wf[rg * 8 + it]);
        acc[rg][0] = mfma16(ha0, wv, acc[rg][0]);
        acc[rg][1] = mfma16(ha1, wv, acc[rg][1]);
      }
    }

    // ---- exchange K-partials via LDS, bf16, separate region (no alias barrier) ----
#pragma unroll
    for (int rg = 0; rg < 4; ++rg) {
      int rowb = rh * 64 + rg * 16 + fr;
      bf16* exr = EXB + (size_t)(kh * 128 + rowb) * 33;
#pragma unroll
      for (int j = 0; j < 4; ++j) {
        exr[fq * 4 + j]      = (bf16)acc[rg][0][j];   // batch = fq*4+j
        exr[16 + fq * 4 + j] = (bf16)acc[rg][1][j];   // batch = 16+fq*4+j
      }
    }
    __syncthreads();

    // ---- pointwise: 2 (b,u) pairs/thread; sum 4 K-partials + gx(LDS); c in regs ----
    const char* gxb = GXL + gx_rd;
    float hv[2]; float cc[2] = {c0, c1};
    unsigned gxw[4];
#pragma unroll
    for (int g2 = 0; g2 < 4; ++g2) gxw[g2] = *(const unsigned*)(gxb + g2 * 1024);
#pragma unroll
    for (int q = 0; q < 2; ++q) {
      int ul = ul_pt + q;
      float gt[4];
#pragma unroll
      for (int g2 = 0; g2 < 4; ++g2) {
        int rowb = g2 * 32 + ul;
        float s = (float)EXB[(size_t)(0 * 128 + rowb) * 33 + b_pt]
                + (float)EXB[(size_t)(1 * 128 + rowb) * 33 + b_pt]
                + (float)EXB[(size_t)(2 * 128 + rowb) * 33 + b_pt]
                + (float)EXB[(size_t)(3 * 128 + rowb) * 33 + b_pt];
        unsigned gb = (q == 0) ? ((gxw[g2] & 0xffffu) << 16) : (gxw[g2] & 0xffff0000u);
        gt[g2] = s + __builtin_bit_cast(float, gb);
      }
      float iv = fminf(fmaxf(__builtin_fmaf(0.2f, gt[0], 0.5f), 0.f), 1.f);
      float fv = fminf(fmaxf(__builtin_fmaf(0.2f, gt[1], 0.5f), 0.f), 1.f);
      float gv = fminf(fmaxf(gt[2], -1.f), 1.f);
      float ov = fminf(fmaxf(__builtin_fmaf(0.2f, gt[3], 0.5f), 0.f), 1.f);
      float c = fv * cc[q] + iv * gv;
      cc[q] = c;
      hv[q] = ov * fminf(fmaxf(c, -1.f), 1.f);
    }
    c0 = cc[0]; c1 = cc[1]; hl0 = hv[0]; hl1 = hv[1];

    // ---- publish h (write-through), drain, flag, then y stores ----
    unsigned hp;
    { union { bf16 h[2]; unsigned u; } pk; pk.h[0] = (bf16)hv[0]; pk.h[1] = (bf16)hv[1]; hp = pk.u; }
    volatile unsigned* hdst =
        (volatile unsigned*)((char*)hbuf + (((size_t)((t + 1) & 1) * 2 + dir) << 16))
        + (((size_t)b_pt * 1024 + ug_pt) >> 1);
    *hdst = hp;
    asm volatile("s_waitcnt vmcnt(0)" ::: "memory");
    __syncthreads();   // all h stores at coherence point before flag release
    if (tid == 0)
      __hip_atomic_store(&flags[bid * 32], t + 1, __ATOMIC_RELAXED, __HIP_MEMORY_SCOPE_AGENT);
    if (yout) {
      *(unsigned*)((char*)yout + (((size_t)tseq * 32 + b_pt) * 2048 + dir * 1024 + ug_pt) * 2) = hp;
    } else {
      float* yd = dout + ((size_t)tseq * 32 + b_pt) * 2048 + dir * 1024 + ug_pt;
      yd[0] = hv[0]; yd[1] = hv[1];
    }
  }

  // ---- final (h,c) states from registers ----
  dout[OUT_Y + soff] = hl0;
  dout[OUT_Y + soff + 1] = hl1;
  dout[OUT_Y + HN_SZ + soff] = c0;
  dout[OUT_Y + HN_SZ + soff + 1] = c1;
}

// ---------------- host launcher ----------------
extern "C" void kernel_launch(void* const* d_in, const int* in_sizes, int n_in,
                              void* d_out, int out_size, void* d_ws, size_t ws_size,
                              hipStream_t stream) {
  const float* x     = (const float*)d_in[0];
  const float* h0    = (const float*)d_in[1];
  // d_in[2] = c0: unused (reference init bug: cn = hn = h0)
  const float* w_ih0 = (const float*)d_in[3];
  const float* w_hh0 = (const float*)d_in[4];
  const float* b_ih0 = (const float*)d_in[5];
  const float* b_hh0 = (const float*)d_in[6];
  const float* w_ihL = (const float*)d_in[7];
  const float* w_hhL = (const float*)d_in[8];
  const float* b_ihL = (const float*)d_in[9];
  const float* b_hhL = (const float*)d_in[10];
  float* dout = (float*)d_out;
  char* ws = (char*)d_ws;

  // ---- workspace carve (bytes) ----
  const size_t OFF_XB   = 0;                         // bf16 [9600][320]
  const size_t OFF_WIH0 = 6144000;                   // bf16 [8192][320]
  const size_t OFF_WIHL = 11386880;                  // bf16 [2][8192][2048]
  const size_t OFF_WHH  = 78495744;                  // bf16 [6][4096][1024]
  const size_t OFF_BSUM = 128827392;                 // f32  [6][4096]
  const size_t OFF_GX   = 128925696;                 // bf16 [2][300][64][4][32][16]
  const size_t OFF_Y0   = 286212096;                 // bf16 [9600][2048]
  const size_t OFF_Y1   = 325533696;                 // bf16 [9600][2048]
  const size_t OFF_HBF  = 364855296;                 // bf16 [2 par][2 dir][32][1024]
  const size_t OFF_FLG  = 365117440;                 // int  [64*32] (128B-padded flags)

  bf16*  xb    = (bf16*)(ws + OFF_XB);
  bf16*  wih0b = (bf16*)(ws + OFF_WIH0);
  bf16*  wihLb = (bf16*)(ws + OFF_WIHL);
  bf16*  whhb  = (bf16*)(ws + OFF_WHH);
  float* bsum  = (float*)(ws + OFF_BSUM);
  bf16*  gx    = (bf16*)(ws + OFF_GX);
  bf16*  y0    = (bf16*)(ws + OFF_Y0);
  bf16*  y1    = (bf16*)(ws + OFF_Y1);
  bf16*  hbuf  = (bf16*)(ws + OFF_HBF);
  int*   flags = (int*)(ws + OFF_FLG);

  auto cvt = [&](const float* s, bf16* d, size_t n) {
    int n8 = (int)(n / 8);
    int grid = (n8 + 255) / 256; if (grid > 2048) grid = 2048;
    k_cvt<<<grid, 256, 0, stream>>>(s, d, n8);
  };

  cvt(x,     xb,    (size_t)MROWS * DIN);
  cvt(w_ih0, wih0b, (size_t)2 * NG * DIN);
  cvt(w_ihL, wihLb, (size_t)2 * 2 * NG * 2048);
  cvt(w_hh0, whhb,  (size_t)2 * NG * NH);
  cvt(w_hhL, whhb + (size_t)2 * NG * NH, (size_t)4 * NG * NH);
  k_bsum<<<96, 256, 0, stream>>>(b_ih0, b_hh0, b_ihL, b_hhL, bsum);

  for (int l = 0; l < 3; ++l) {
    const bf16* A = (l == 0) ? xb : (l == 1 ? y0 : y1);
    int K = (l == 0) ? DIN : 2048;
    const bf16* Bw = (l == 0) ? wih0b : (wihLb + (size_t)(l - 1) * 2 * NG * 2048);
    k_gemm_gx<<<dim3(64, 75), 256, 0, stream>>>(A, Bw, bsum + (size_t)l * 2 * NG, gx, K);

    k_init<<<256, 256, 0, stream>>>(h0, hbuf, flags, l);

    const bf16* whh_l = whhb + (size_t)l * 2 * NG * NH;
    bf16* yout = (l == 0) ? y0 : (l == 1 ? y1 : nullptr);
    k_rec<<<64, 512, 0, stream>>>(whh_l, gx, h0, hbuf, flags, yout, dout, l);
  }
  (void)in_sizes; (void)n_in; (void)out_size; (void)ws_size;
}

// Round 10
// 4924.700 us; speedup vs baseline: 1.2019x; 1.1912x over previous
//
#include <hip/hip_runtime.h>

typedef __bf16 bf16;
typedef __attribute__((ext_vector_type(8))) __bf16 bf16x8;
typedef __attribute__((ext_vector_type(4))) float f32x4;

#define GLOBAL_AS __attribute__((address_space(1)))
#define LDS_AS __attribute__((address_space(3)))

__device__ __forceinline__ void gload_lds16(const void* g, void* l) {
  __builtin_amdgcn_global_load_lds((const GLOBAL_AS void*)g, (LDS_AS void*)l, 16, 0, 0);
}
// cache-bypassing variant (sc0|sc1 = system scope): coherent-read-through
__device__ __forceinline__ void gload_lds16_cc(const void* g, void* l) {
  __builtin_amdgcn_global_load_lds((const GLOBAL_AS void*)g, (LDS_AS void*)l, 16, 0, 0x11);
}

__device__ __forceinline__ f32x4 mfma16(bf16x8 a, bf16x8 b, f32x4 c) {
  return __builtin_amdgcn_mfma_f32_16x16x32_bf16(a, b, c, 0, 0, 0);
}

// ---------------- constants ----------------
#define T_SEQ 300
#define NBATCH 32
#define DIN 320
#define NH 1024
#define NG 4096              // 4*NH
#define MROWS 9600           // T_SEQ*NBATCH
#define OUT_Y 19660800       // T*B*2H
#define HN_SZ 196608         // 6*32*1024

// ---------------- f32 -> bf16 convert ----------------
__global__ __launch_bounds__(256) void k_cvt(const float* __restrict__ src,
                                             bf16* __restrict__ dst, int n8) {
  int stride = gridDim.x * blockDim.x;
  for (int i = blockIdx.x * blockDim.x + threadIdx.x; i < n8; i += stride) {
    const float* s = src + (size_t)i * 8;
    f32x4 a = *(const f32x4*)s;
    f32x4 b = *(const f32x4*)(s + 4);
    bf16x8 o;
#pragma unroll
    for (int j = 0; j < 4; ++j) { o[j] = (bf16)a[j]; o[j + 4] = (bf16)b[j]; }
    *(bf16x8*)(dst + (size_t)i * 8) = o;
  }
}

// ---------------- bias sums: bsum[l][dir][4096] = b_ih + b_hh ----------------
__global__ __launch_bounds__(256) void k_bsum(const float* __restrict__ bih0,
                                              const float* __restrict__ bhh0,
                                              const float* __restrict__ bihL,
                                              const float* __restrict__ bhhL,
                                              float* __restrict__ bsum) {
  int i = blockIdx.x * 256 + threadIdx.x;  // n = 6*4096 = 24576
  if (i < 2 * NG) bsum[i] = bih0[i] + bhh0[i];
  else            bsum[i] = bihL[i - 2 * NG] + bhhL[i - 2 * NG];
}

// ---------------- GX GEMM: gxT[dir][t][gate][b][u] = A[M,K] * W[8192,K]^T + bias ----------------
__global__ __launch_bounds__(256) void k_gemm_gx(const bf16* __restrict__ A,
                                                 const bf16* __restrict__ Bw,
                                                 const float* __restrict__ bias,
                                                 bf16* __restrict__ gxout, int K) {
  __shared__ bf16 As[128 * 32];
  __shared__ bf16 Bs[128 * 32];
  const int t = threadIdx.x;
  const int m0 = blockIdx.y * 128, n0 = blockIdx.x * 128;
  const int lane = t & 63, wid = t >> 6;
  const int wr = wid >> 1, wc = wid & 1;
  const int fr = lane & 15, fq = lane >> 4;
  f32x4 acc[4][4] = {};
  for (int k0 = 0; k0 < K; k0 += 32) {
#pragma unroll
    for (int r = 0; r < 2; ++r) {
      int idx = r * 256 + t;
      int row = idx >> 2, kk = (idx & 3) * 8;
      gload_lds16(A + (size_t)(m0 + row) * K + k0 + kk, As + (size_t)idx * 8);
      gload_lds16(Bw + (size_t)(n0 + row) * K + k0 + kk, Bs + (size_t)idx * 8);
    }
    asm volatile("s_waitcnt vmcnt(0)" ::: "memory");
    __syncthreads();
    bf16x8 af[4], bf_[4];
#pragma unroll
    for (int i2 = 0; i2 < 4; ++i2) {
      af[i2]  = *(const bf16x8*)(As + (wr * 64 + i2 * 16 + fr) * 32 + fq * 8);
      bf_[i2] = *(const bf16x8*)(Bs + (wc * 64 + i2 * 16 + fr) * 32 + fq * 8);
    }
#pragma unroll
    for (int mi = 0; mi < 4; ++mi)
#pragma unroll
      for (int ni = 0; ni < 4; ++ni)
        acc[mi][ni] = mfma16(af[mi], bf_[ni], acc[mi][ni]);
    __syncthreads();
  }
  // epilogue: add bias, scatter to gxT[dir][t][g][b][u]
#pragma unroll
  for (int ni = 0; ni < 4; ++ni) {
    int col = n0 + wc * 64 + ni * 16 + fr;
    float bv = bias[col];
    int dir = col >> 12, grow = col & (NG - 1);
    int gg = grow >> 10, uu = grow & 1023;
    bf16* base = gxout + ((size_t)dir * 300 * 4 + gg) * 32768 + uu;
#pragma unroll
    for (int mi = 0; mi < 4; ++mi) {
#pragma unroll
      for (int j = 0; j < 4; ++j) {
        int row = m0 + wr * 64 + mi * 16 + fq * 4 + j;
        int tt = row >> 5, b = row & 31;
        base[(size_t)tt * 131072 + b * 1024] = (bf16)(acc[mi][ni][j] + bv);
      }
    }
  }
}

// ---------------- per-layer init: h buffer (par 0) + flags ----------------
__global__ __launch_bounds__(256) void k_init(const float* __restrict__ h0,
                                              bf16* __restrict__ hbuf,
                                              int* __restrict__ flags, int layer) {
  int i = blockIdx.x * 256 + threadIdx.x;  // 65536 = [2 dir][32][1024]
  hbuf[i] = (bf16)h0[(size_t)layer * 65536 + i];
  if (blockIdx.x == 0 && threadIdx.x < 64) flags[threadIdx.x] = 0;
}

// ---------------- persistent recurrence: one launch per layer ----------------
// EXACT round-5 structure (proven 1244 us/layer) + ONE change: gx(t+1) prefetch
// issued after the flag release into a double-buffered LDS slot, so its HBM
// latency drains under flag-propagation + poll + h-stage of the next step.
__global__ __launch_bounds__(512, 1) void k_rec(
    const bf16* __restrict__ whh,   // [2][4096][1024] (this layer)
    const bf16* __restrict__ gxT,   // [2][300][4][32][1024] bf16, biases folded
    const float* __restrict__ h0,   // [6][32][1024]
    bf16* __restrict__ hbuf,        // [2 par][2 dir][32][1024]
    int* __restrict__ flags,        // [64], zeroed by k_init
    bf16* __restrict__ yout,        // [9600][2048] or null (layer 2)
    float* __restrict__ dout,
    int layer) {
  __shared__ char smem_[83968];
  // [0..65536)       h tile (XOR-swizzled rows), dead after MFMA phase
  // [0..67584)       EX exchange [4 kh][128 row][33] f32 (aliases h tile)
  // [67584..83968)   GXL gx double buffer [2][4 g][32 b][32 u] bf16 = 2 x 8 KB
  float* EX = (float*)smem_;
  char* GXL = smem_ + 67584;

  const int tid = threadIdx.x;
  const int bid = blockIdx.x;
  const int dir = bid >> 5;
  const int rank = bid & 31;
  const int u0 = rank << 5;
  const int w = tid >> 6, lane = tid & 63;
  const int fr = lane & 15, fq = lane >> 4;
  const int kh = w >> 1, rh = w & 1;

  // ---- weights -> registers (64 rows x K=256 per wave = 128 regs/lane), pinned ----
  f32x4 wf[32];
#pragma unroll
  for (int rg = 0; rg < 4; ++rg) {
    int rowb = rh * 64 + rg * 16 + fr;  // block gate-row 0..127 (= g*32 + u_local)
    const bf16* Wp = whh + ((size_t)dir * 4096 + (rowb >> 5) * 1024 + u0 + (rowb & 31)) * 1024
                     + kh * 256 + fq * 8;
#pragma unroll
    for (int it = 0; it < 8; ++it) wf[rg * 8 + it] = *(const f32x4*)(Wp + it * 32);
  }
#pragma unroll
  for (int i = 0; i < 32; ++i) asm volatile("" : "+v"(wf[i]));

  // ---- cell state in registers; c init = h0 (reference's cn=hn bug) ----
  const int b_pt = tid >> 4;           // batch 0..31
  const int ul_pt = (tid & 15) << 1;   // local unit 0,2,..,30
  const int ug_pt = u0 + ul_pt;
  const size_t soff = ((size_t)layer * 2 + dir) * 32768 + (size_t)b_pt * 1024 + ug_pt;
  float c0 = h0[soff], c1 = h0[soff + 1];
  float hl0 = 0.f, hl1 = 0.f;

  // gx DMA mapping: thread -> (gate, b, 16B quarter)  [round-5 strided layout]
  const int gg = tid >> 7, sub = tid & 127;
  const size_t gx_base0 = ((size_t)dir * 1200 + gg) * 32768
                          + (size_t)(sub >> 2) * 1024 + u0 + (sub & 3) * 8;

  // h-stage source offsets (t-invariant): linear LDS dest, inverse-swizzled source
  int srcoff[8];
#pragma unroll
  for (int r = 0; r < 8; ++r) {
    int d = r * 8192 + tid * 16;
    int row = d >> 11, colb = d & 2047;
    srcoff[r] = row * 2048 + (colb ^ ((row & 7) << 4));
  }
  const int swz = (fr & 7) << 4;

  // ---- prologue: gx(0) DMA into buffer 0 (flies during weight load) ----
  {
    const int ts0 = dir ? (T_SEQ - 1) : 0;
    gload_lds16(gxT + gx_base0 + (size_t)ts0 * 131072, GXL + tid * 16);
  }

#pragma unroll 1
  for (int t = 0; t < T_SEQ; ++t) {
    const int tseq = dir ? (T_SEQ - 1 - t) : t;

    // ---- barrier: all same-dir blocks published h(t-1) ----
    if (tid < 32) {
      while (__hip_atomic_load(&flags[dir * 32 + tid], __ATOMIC_RELAXED,
                               __HIP_MEMORY_SCOPE_AGENT) < t)
        __builtin_amdgcn_s_sleep(1);
    }
    __syncthreads();   // execution order: no thread reads h before poll passes

    // ---- stage h(dir) 64KB -> LDS via coherence-point bypass loads ----
    const char* hsrc = (const char*)hbuf + (((size_t)(t & 1) * 2 + dir) << 16);
#pragma unroll
    for (int r = 0; r < 8; ++r)
      gload_lds16_cc(hsrc + srcoff[r], smem_ + r * 8192 + tid * 16);
    asm volatile("s_waitcnt vmcnt(0)" ::: "memory");   // h tile + prefetched gx landed
    __syncthreads();

    // ---- matvec: K-split-4, 64 MFMA from LDS(h) x reg(W); 16KB LDS read/wave ----
    f32x4 acc[4][2] = {};
    const char* hb0 = smem_ + fr * 2048;
#pragma unroll
    for (int it = 0; it < 8; ++it) {
      int col = kh * 512 + it * 64 + fq * 16;
      bf16x8 ha0 = *(const bf16x8*)(hb0 + (col ^ swz));
      bf16x8 ha1 = *(const bf16x8*)(hb0 + 32768 + (col ^ swz));
#pragma unroll
      for (int rg = 0; rg < 4; ++rg) {
        bf16x8 wv = __builtin_bit_cast(bf16x8, wf[rg * 8 + it]);
        acc[rg][0] = mfma16(ha0, wv, acc[rg][0]);
        acc[rg][1] = mfma16(ha1, wv, acc[rg][1]);
      }
    }
    __syncthreads();  // all waves done reading h tile; EX aliases it

    // ---- exchange K-partials via LDS (f32, stride 33) ----
#pragma unroll
    for (int rg = 0; rg < 4; ++rg) {
      int rowb = rh * 64 + rg * 16 + fr;
      float* exr = EX + (size_t)(kh * 128 + rowb) * 33;
#pragma unroll
      for (int j = 0; j < 4; ++j) {
        exr[fq * 4 + j]      = acc[rg][0][j];   // batch = fq*4+j
        exr[16 + fq * 4 + j] = acc[rg][1][j];   // batch = 16+fq*4+j
      }
    }
    __syncthreads();

    // ---- pointwise: 2 (b,u) pairs/thread; sum 4 K-partials + gx(LDS); c in regs ----
    const bf16* gxb = (const bf16*)(GXL + (t & 1) * 8192);
    float hv[2]; float cc[2] = {c0, c1};
#pragma unroll
    for (int q = 0; q < 2; ++q) {
      int ul = ul_pt + q;
      float gt[4];
#pragma unroll
      for (int g2 = 0; g2 < 4; ++g2) {
        int rowb = g2 * 32 + ul;
        float s = EX[(size_t)(0 * 128 + rowb) * 33 + b_pt]
                + EX[(size_t)(1 * 128 + rowb) * 33 + b_pt]
                + EX[(size_t)(2 * 128 + rowb) * 33 + b_pt]
                + EX[(size_t)(3 * 128 + rowb) * 33 + b_pt];
        gt[g2] = s + (float)gxb[(g2 * 32 + b_pt) * 32 + ul];
      }
      float iv = fminf(fmaxf(__builtin_fmaf(0.2f, gt[0], 0.5f), 0.f), 1.f);
      float fv = fminf(fmaxf(__builtin_fmaf(0.2f, gt[1], 0.5f), 0.f), 1.f);
      float gv = fminf(fmaxf(gt[2], -1.f), 1.f);
      float ov = fminf(fmaxf(__builtin_fmaf(0.2f, gt[3], 0.5f), 0.f), 1.f);
      float c = fv * cc[q] + iv * gv;
      cc[q] = c;
      hv[q] = ov * fminf(fmaxf(c, -1.f), 1.f);
    }
    c0 = cc[0]; c1 = cc[1]; hl0 = hv[0]; hl1 = hv[1];

    // ---- publish h (volatile write-through), drain, flag ----
    unsigned hp;
    { union { bf16 h[2]; unsigned u; } pk; pk.h[0] = (bf16)hv[0]; pk.h[1] = (bf16)hv[1]; hp = pk.u; }
    volatile unsigned* hdst =
        (volatile unsigned*)((char*)hbuf + (((size_t)((t + 1) & 1) * 2 + dir) << 16))
        + (((size_t)b_pt * 1024 + ug_pt) >> 1);
    *hdst = hp;
    asm volatile("s_waitcnt vmcnt(0)" ::: "memory");
    __syncthreads();   // all h stores at coherence point before flag release
    if (tid == 0)
      __hip_atomic_store(&flags[bid], t + 1, __ATOMIC_RELAXED, __HIP_MEMORY_SCOPE_AGENT);

    // ---- off-path: y stores + gx(t+1) prefetch (retire at next h-stage vmcnt) ----
    if (yout) {
      *(unsigned*)((char*)yout + (((size_t)tseq * 32 + b_pt) * 2048 + dir * 1024 + ug_pt) * 2) = hp;
    } else {
      float* yd = dout + ((size_t)tseq * 32 + b_pt) * 2048 + dir * 1024 + ug_pt;
      yd[0] = hv[0]; yd[1] = hv[1];
    }
    if (t + 1 < T_SEQ) {
      const int tn = dir ? (T_SEQ - 2 - t) : (t + 1);
      gload_lds16(gxT + gx_base0 + (size_t)tn * 131072,
                  GXL + ((t + 1) & 1) * 8192 + tid * 16);
    }
  }

  // ---- final (h,c) states from registers ----
  dout[OUT_Y + soff] = hl0;
  dout[OUT_Y + soff + 1] = hl1;
  dout[OUT_Y + HN_SZ + soff] = c0;
  dout[OUT_Y + HN_SZ + soff + 1] = c1;
}

// ---------------- host launcher ----------------
extern "C" void kernel_launch(void* const* d_in, const int* in_sizes, int n_in,
                              void* d_out, int out_size, void* d_ws, size_t ws_size,
                              hipStream_t stream) {
  const float* x     = (const float*)d_in[0];
  const float* h0    = (const float*)d_in[1];
  // d_in[2] = c0: unused (reference init bug: cn = hn = h0)
  const float* w_ih0 = (const float*)d_in[3];
  const float* w_hh0 = (const float*)d_in[4];
  const float* b_ih0 = (const float*)d_in[5];
  const float* b_hh0 = (const float*)d_in[6];
  const float* w_ihL = (const float*)d_in[7];
  const float* w_hhL = (const float*)d_in[8];
  const float* b_ihL = (const float*)d_in[9];
  const float* b_hhL = (const float*)d_in[10];
  float* dout = (float*)d_out;
  char* ws = (char*)d_ws;

  // ---- workspace carve (bytes) ----
  const size_t OFF_XB   = 0;                         // bf16 [9600][320]
  const size_t OFF_WIH0 = 6144000;                   // bf16 [8192][320]
  const size_t OFF_WIHL = 11386880;                  // bf16 [2][8192][2048]
  const size_t OFF_WHH  = 78495744;                  // bf16 [6][4096][1024]
  const size_t OFF_BSUM = 128827392;                 // f32  [6][4096]
  const size_t OFF_GX   = 128925696;                 // bf16 [2][300][4][32][1024]
  const size_t OFF_Y0   = 286212096;                 // bf16 [9600][2048]
  const size_t OFF_Y1   = 325533696;                 // bf16 [9600][2048]
  const size_t OFF_HBF  = 364855296;                 // bf16 [2 par][2 dir][32][1024]
  const size_t OFF_FLG  = 365117440;                 // int  [64]

  bf16*  xb    = (bf16*)(ws + OFF_XB);
  bf16*  wih0b = (bf16*)(ws + OFF_WIH0);
  bf16*  wihLb = (bf16*)(ws + OFF_WIHL);
  bf16*  whhb  = (bf16*)(ws + OFF_WHH);
  float* bsum  = (float*)(ws + OFF_BSUM);
  bf16*  gx    = (bf16*)(ws + OFF_GX);
  bf16*  y0    = (bf16*)(ws + OFF_Y0);
  bf16*  y1    = (bf16*)(ws + OFF_Y1);
  bf16*  hbuf  = (bf16*)(ws + OFF_HBF);
  int*   flags = (int*)(ws + OFF_FLG);

  auto cvt = [&](const float* s, bf16* d, size_t n) {
    int n8 = (int)(n / 8);
    int grid = (n8 + 255) / 256; if (grid > 2048) grid = 2048;
    k_cvt<<<grid, 256, 0, stream>>>(s, d, n8);
  };

  cvt(x,     xb,    (size_t)MROWS * DIN);
  cvt(w_ih0, wih0b, (size_t)2 * NG * DIN);
  cvt(w_ihL, wihLb, (size_t)2 * 2 * NG * 2048);
  cvt(w_hh0, whhb,  (size_t)2 * NG * NH);
  cvt(w_hhL, whhb + (size_t)2 * NG * NH, (size_t)4 * NG * NH);
  k_bsum<<<96, 256, 0, stream>>>(b_ih0, b_hh0, b_ihL, b_hhL, bsum);

  for (int l = 0; l < 3; ++l) {
    const bf16* A = (l == 0) ? xb : (l == 1 ? y0 : y1);
    int K = (l == 0) ? DIN : 2048;
    const bf16* Bw = (l == 0) ? wih0b : (wihLb + (size_t)(l - 1) * 2 * NG * 2048);
    k_gemm_gx<<<dim3(64, 75), 256, 0, stream>>>(A, Bw, bsum + (size_t)l * 2 * NG, gx, K);

    k_init<<<256, 256, 0, stream>>>(h0, hbuf, flags, l);

    const bf16* whh_l = whhb + (size_t)l * 2 * NG * NH;
    bf16* yout = (l == 0) ? y0 : (l == 1 ? y1 : nullptr);
    k_rec<<<64, 512, 0, stream>>>(whh_l, gx, h0, hbuf, flags, yout, dout, l);
  }
  (void)in_sizes; (void)n_in; (void)out_size; (void)ws_size;
}